// Round 5
// baseline (455.929 us; speedup 1.0000x reference)
//
#include <hip/hip_runtime.h>
#include <math.h>

#define B  32
#define U  4096
#define D  512     // D_DEC == D_ENC
#define H  4
#define HD 128
#define CK 31
#define CF 32
#define AU 512

#define BPB    32           // block-partials per batch row (U / 128 rows-per-block)
#define ROWS_W 32           // u-rows per wave

static __device__ __forceinline__ float readlane_f(float v, int l) {
    return __int_as_float(__builtin_amdgcn_readlane(__float_as_int(v), l));
}

// ---------------- Kernel A: phi_s, v = Wpsi @ phi_s, ck = conv (x) Wloc ----
__global__ __launch_bounds__(256) void prep_kernel(
    const float* __restrict__ dec,    // (B,512)
    const float* __restrict__ Wphi,   // (H,512,128)
    const float* __restrict__ bphi,   // (H,128)
    const float* __restrict__ Wpsi,   // (H,512,128)
    const float* __restrict__ bpsi,   // (H,128)
    const float* __restrict__ convk,  // (31,1,32)
    const float* __restrict__ Wloc,   // (32,4)
    float* __restrict__ ws_v,         // (B,H,512)
    float* __restrict__ ws_const,     // (B,H)
    float* __restrict__ ws_ck)        // (31,4)
{
    __shared__ float decs[D];
    __shared__ float phis2[2][HD];
    __shared__ float phis[HD];
    const int b = blockIdx.x / H, h = blockIdx.x % H;
    const int tid = threadIdx.x;

    for (int i = tid; i < D; i += 256) decs[i] = dec[b * D + i];
    __syncthreads();

    // phi projection with all 256 threads: split K in half
    {
        const int k = tid & 127, half = tid >> 7;
        const int d0 = half * 256;
        float acc = 0.f;
        const float* wp = Wphi + (size_t)h * D * HD + (size_t)d0 * HD + k;
        #pragma unroll 8
        for (int d = 0; d < 256; ++d) acc += decs[d0 + d] * wp[(size_t)d * HD];
        phis2[half][k] = acc;
    }
    __syncthreads();
    if (tid < HD) phis[tid] = phis2[0][tid] + phis2[1][tid] + bphi[h * HD + tid];
    __syncthreads();

    if (tid == 0) {
        float c = 0.f;
        for (int k = 0; k < HD; ++k) c += phis[k] * bpsi[h * HD + k];
        ws_const[b * H + h] = c;
    }

    for (int e = tid; e < D; e += 256) {
        const float* wq = Wpsi + ((size_t)h * D + e) * HD;
        float acc = 0.f;
        #pragma unroll 8
        for (int k = 0; k < HD; ++k) acc += wq[k] * phis[k];
        ws_v[((size_t)b * H + h) * D + e] = acc;
    }

    if (blockIdx.x == 0 && tid < CK * H) {
        int t = tid / H, hh = tid % H;
        float acc = 0.f;
        for (int f = 0; f < CF; ++f) acc += convk[t * CF + f] * Wloc[f * H + hh];
        ws_ck[t * H + hh] = acc;
    }
}

// ---- Pass 1 (fused): energy + online-softmax partial context, ONE enc read
// 2-row-deep register prefetch; energy accumulated in registers and stored
// coalesced per wave (no scattered stores in the hot loop).
__global__ __launch_bounds__(256, 4) void fused_pass1(
    const float* __restrict__ enc,     // (B,U,512)
    const float* __restrict__ prevw,   // (B,U)
    const float* __restrict__ ws_v,    // (B,H,512)
    const float* __restrict__ ws_const,// (B,H)
    const float* __restrict__ ws_ck,   // (31,4)
    float* __restrict__ energy,        // (B,H,U)
    float* __restrict__ pctx,          // (B,BPB,H,512)
    float* __restrict__ pms)           // (B,BPB,H,2)  m,s
{
    const int b    = blockIdx.y;
    const int blk  = blockIdx.x;              // 0..BPB-1
    const int tid  = threadIdx.x;
    const int lane = tid & 63;
    const int wave = tid >> 6;
    const int ubase = (blk * 4 + wave) * ROWS_W;

    __shared__ float lctx[4][H][D];   // 32 KB
    __shared__ float lms[4][H][2];
    __shared__ float lalpha[H][4];

    // v fragments: lane owns d = lane*8 .. lane*8+7
    float4 v0[H], v1[H];
    #pragma unroll
    for (int h = 0; h < H; ++h) {
        const float* vp = ws_v + ((size_t)b * H + h) * D + lane * 8;
        v0[h] = *(const float4*)vp;
        v1[h] = *(const float4*)(vp + 4);
    }
    float ckr[H] = {0.f, 0.f, 0.f, 0.f};
    if (lane < CK) {
        #pragma unroll
        for (int h = 0; h < H; ++h) ckr[h] = ws_ck[lane * H + h];
    }
    float ct[H];
    #pragma unroll
    for (int h = 0; h < H; ++h) ct[h] = ws_const[b * H + h];

    // prevw window preload: row r, lane l needs prevw[ubase + r + l - 15],
    // r + l <= 62 < 64 -> one 64-lane register covers the strip.
    float w0;
    {
        const int gi = ubase - 15 + lane;
        w0 = (gi >= 0 && gi < U) ? prevw[b * U + gi] : 0.f;
    }

    float m0 = -3.402823466e38f, m1 = m0, m2 = m0, m3 = m0;
    float s0 = 0.f, s1 = 0.f, s2 = 0.f, s3 = 0.f;
    float4 z = {0.f, 0.f, 0.f, 0.f};
    float4 c00 = z, c01 = z, c10 = z, c11 = z, c20 = z, c21 = z, c30 = z, c31 = z;
    float ea0 = 0.f, ea1 = 0.f, ea2 = 0.f, ea3 = 0.f;   // energy row accumulators

    const bool b16 = (lane & 16) != 0;
    const bool b32 = (lane & 32) != 0;

    const float* encb = enc + ((size_t)b * U + ubase) * D + lane * 8;
    // 2-row-deep rotating prefetch
    float4 eA0 = *(const float4*)encb;
    float4 eA1 = *(const float4*)(encb + 4);
    float4 eB0 = *(const float4*)(encb + D);
    float4 eB1 = *(const float4*)(encb + D + 4);

    #pragma unroll 2
    for (int r = 0; r < ROWS_W; ++r) {
        float4 eC0, eC1;
        if (r < ROWS_W - 2) {
            const float* nx = encb + (size_t)(r + 2) * D;
            eC0 = *(const float4*)nx;
            eC1 = *(const float4*)(nx + 4);
        }
        // conv window value via cross-lane pull (no per-row global load)
        float pw = __int_as_float(
            __builtin_amdgcn_ds_bpermute((r + lane) << 2, __float_as_int(w0)));

        float p0 = pw * ckr[0]
            + eA0.x*v0[0].x + eA0.y*v0[0].y + eA0.z*v0[0].z + eA0.w*v0[0].w
            + eA1.x*v1[0].x + eA1.y*v1[0].y + eA1.z*v1[0].z + eA1.w*v1[0].w;
        float p1 = pw * ckr[1]
            + eA0.x*v0[1].x + eA0.y*v0[1].y + eA0.z*v0[1].z + eA0.w*v0[1].w
            + eA1.x*v1[1].x + eA1.y*v1[1].y + eA1.z*v1[1].z + eA1.w*v1[1].w;
        float p2 = pw * ckr[2]
            + eA0.x*v0[2].x + eA0.y*v0[2].y + eA0.z*v0[2].z + eA0.w*v0[2].w
            + eA1.x*v1[2].x + eA1.y*v1[2].y + eA1.z*v1[2].z + eA1.w*v1[2].w;
        float p3 = pw * ckr[3]
            + eA0.x*v0[3].x + eA0.y*v0[3].y + eA0.z*v0[3].z + eA0.w*v0[3].w
            + eA1.x*v1[3].x + eA1.y*v1[3].y + eA1.z*v1[3].z + eA1.w*v1[3].w;

        // ---- pairwise exchange reduce: group g of 16 lanes ends with head g
        float keepA = b16 ? p1 : p0, sendA = b16 ? p0 : p1;
        float a  = keepA + __shfl_xor(sendA, 16);
        float keepB = b16 ? p3 : p2, sendB = b16 ? p2 : p3;
        float bb = keepB + __shfl_xor(sendB, 16);
        float keepC = b32 ? bb : a, sendC = b32 ? a : bb;
        float c = keepC + __shfl_xor(sendC, 32);
        c += __shfl_xor(c, 1);
        c += __shfl_xor(c, 2);
        c += __shfl_xor(c, 4);
        c += __shfl_xor(c, 8);
        // wave-uniform broadcast via readlane (SGPR-resident)
        float eh0 = readlane_f(c, 0)  + ct[0];
        float eh1 = readlane_f(c, 16) + ct[1];
        float eh2 = readlane_f(c, 32) + ct[2];
        float eh3 = readlane_f(c, 48) + ct[3];

        // accumulate energy rows in registers (lane r holds row r)
        ea0 = (lane == r) ? eh0 : ea0;
        ea1 = (lane == r) ? eh1 : ea1;
        ea2 = (lane == r) ? eh2 : ea2;
        ea3 = (lane == r) ? eh3 : ea3;

        // ---- online softmax update (wave-uniform branch) ----
        float mn0 = fmaxf(m0, eh0), mn1 = fmaxf(m1, eh1);
        float mn2 = fmaxf(m2, eh2), mn3 = fmaxf(m3, eh3);
        if (mn0 > m0 || mn1 > m1 || mn2 > m2 || mn3 > m3) {
            float a0 = __expf(m0 - mn0), a1 = __expf(m1 - mn1);
            float a2 = __expf(m2 - mn2), a3 = __expf(m3 - mn3);
            s0 *= a0; s1 *= a1; s2 *= a2; s3 *= a3;
            c00.x*=a0; c00.y*=a0; c00.z*=a0; c00.w*=a0; c01.x*=a0; c01.y*=a0; c01.z*=a0; c01.w*=a0;
            c10.x*=a1; c10.y*=a1; c10.z*=a1; c10.w*=a1; c11.x*=a1; c11.y*=a1; c11.z*=a1; c11.w*=a1;
            c20.x*=a2; c20.y*=a2; c20.z*=a2; c20.w*=a2; c21.x*=a2; c21.y*=a2; c21.z*=a2; c21.w*=a2;
            c30.x*=a3; c30.y*=a3; c30.z*=a3; c30.w*=a3; c31.x*=a3; c31.y*=a3; c31.z*=a3; c31.w*=a3;
            m0 = mn0; m1 = mn1; m2 = mn2; m3 = mn3;
        }
        float w0e = __expf(eh0 - m0), w1e = __expf(eh1 - m1);
        float w2e = __expf(eh2 - m2), w3e = __expf(eh3 - m3);
        s0 += w0e; s1 += w1e; s2 += w2e; s3 += w3e;
        c00.x += w0e*eA0.x; c00.y += w0e*eA0.y; c00.z += w0e*eA0.z; c00.w += w0e*eA0.w;
        c01.x += w0e*eA1.x; c01.y += w0e*eA1.y; c01.z += w0e*eA1.z; c01.w += w0e*eA1.w;
        c10.x += w1e*eA0.x; c10.y += w1e*eA0.y; c10.z += w1e*eA0.z; c10.w += w1e*eA0.w;
        c11.x += w1e*eA1.x; c11.y += w1e*eA1.y; c11.z += w1e*eA1.z; c11.w += w1e*eA1.w;
        c20.x += w2e*eA0.x; c20.y += w2e*eA0.y; c20.z += w2e*eA0.z; c20.w += w2e*eA0.w;
        c21.x += w2e*eA1.x; c21.y += w2e*eA1.y; c21.z += w2e*eA1.z; c21.w += w2e*eA1.w;
        c30.x += w3e*eA0.x; c30.y += w3e*eA0.y; c30.z += w3e*eA0.z; c30.w += w3e*eA0.w;
        c31.x += w3e*eA1.x; c31.y += w3e*eA1.y; c31.z += w3e*eA1.z; c31.w += w3e*eA1.w;

        eA0 = eB0; eA1 = eB1;
        eB0 = eC0; eB1 = eC1;
    }

    // coalesced energy store: 4 x 128B per wave
    if (lane < ROWS_W) {
        const int u = ubase + lane;
        energy[((size_t)b * H + 0) * U + u] = ea0;
        energy[((size_t)b * H + 1) * U + u] = ea1;
        energy[((size_t)b * H + 2) * U + u] = ea2;
        energy[((size_t)b * H + 3) * U + u] = ea3;
    }

    // ---- block-level merge of the 4 wave partials via LDS ----
    *(float4*)&lctx[wave][0][lane * 8]     = c00;
    *(float4*)&lctx[wave][0][lane * 8 + 4] = c01;
    *(float4*)&lctx[wave][1][lane * 8]     = c10;
    *(float4*)&lctx[wave][1][lane * 8 + 4] = c11;
    *(float4*)&lctx[wave][2][lane * 8]     = c20;
    *(float4*)&lctx[wave][2][lane * 8 + 4] = c21;
    *(float4*)&lctx[wave][3][lane * 8]     = c30;
    *(float4*)&lctx[wave][3][lane * 8 + 4] = c31;
    if (lane == 0) {
        lms[wave][0][0] = m0; lms[wave][0][1] = s0;
        lms[wave][1][0] = m1; lms[wave][1][1] = s1;
        lms[wave][2][0] = m2; lms[wave][2][1] = s2;
        lms[wave][3][0] = m3; lms[wave][3][1] = s3;
    }
    __syncthreads();

    const size_t pbase = ((size_t)(b * BPB + blk)) * H;
    if (tid < H) {
        const int h = tid;
        float M = fmaxf(fmaxf(lms[0][h][0], lms[1][h][0]),
                        fmaxf(lms[2][h][0], lms[3][h][0]));
        float S = 0.f;
        #pragma unroll
        for (int w = 0; w < 4; ++w) {
            float al = __expf(lms[w][h][0] - M);
            lalpha[h][w] = al;
            S += al * lms[w][h][1];
        }
        pms[(pbase + h) * 2]     = M;
        pms[(pbase + h) * 2 + 1] = S;
    }
    __syncthreads();

    #pragma unroll
    for (int h = 0; h < H; ++h) {
        const float a0 = lalpha[h][0], a1 = lalpha[h][1];
        const float a2 = lalpha[h][2], a3 = lalpha[h][3];
        #pragma unroll
        for (int half = 0; half < 2; ++half) {
            const int d = tid + half * 256;
            float val = a0 * lctx[0][h][d] + a1 * lctx[1][h][d]
                      + a2 * lctx[2][h][d] + a3 * lctx[3][h][d];
            pctx[(pbase + h) * D + d] = val;
        }
    }
}

// ---- Pass 2: combine per-block partials -> ctx (B,H,512), save M,S -------
__global__ __launch_bounds__(256) void combine_kernel(
    const float* __restrict__ pctx,  // (B,BPB,H,512)
    const float* __restrict__ pms,   // (B,BPB,H,2)
    float* __restrict__ ctx,         // (B,H,512)
    float* __restrict__ MS)          // (B,H,2)
{
    const int bh = blockIdx.x;       // b*H+h
    const int b = bh >> 2, h = bh & 3;
    const int tid = threadIdx.x;
    __shared__ float sm[BPB], ss[BPB], salpha[BPB];
    __shared__ float MSsh[2];

    if (tid < BPB) {
        sm[tid] = pms[(((size_t)b * BPB + tid) * H + h) * 2];
        ss[tid] = pms[(((size_t)b * BPB + tid) * H + h) * 2 + 1];
    }
    __syncthreads();
    if (tid == 0) {
        float M = -3.402823466e38f;
        for (int i = 0; i < BPB; ++i) M = fmaxf(M, sm[i]);
        float S = 0.f;
        for (int i = 0; i < BPB; ++i) {
            float al = __expf(sm[i] - M);
            salpha[i] = al;
            S += al * ss[i];
        }
        MSsh[0] = M; MSsh[1] = S;
        MS[bh * 2] = M; MS[bh * 2 + 1] = S;
    }
    __syncthreads();
    const float invS = 1.0f / MSsh[1];

    float acc0 = 0.f, acc1 = 0.f;
    const float* base = pctx + ((size_t)b * BPB * H + h) * D;
    #pragma unroll 4
    for (int i = 0; i < BPB; ++i) {
        float al = salpha[i];
        const float* p = base + (size_t)i * H * D;
        acc0 += al * p[tid];
        acc1 += al * p[tid + 256];
    }
    ctx[(size_t)bh * D + tid]       = acc0 * invS;
    ctx[(size_t)bh * D + tid + 256] = acc1 * invS;
}

// ---- Pass 3: attention_weights = mean_h softmax(energy), 256 blocks ------
__global__ __launch_bounds__(256) void attw_kernel(
    const float* __restrict__ energy,  // (B,H,U)
    const float* __restrict__ MS,      // (B,H,2)
    float* __restrict__ attw)          // (B,U)
{
    const int b = blockIdx.y, tid = threadIdx.x;
    const int u0 = blockIdx.x * 512;
    float M[H], iS[H];
    #pragma unroll
    for (int h = 0; h < H; ++h) {
        M[h]  = MS[(b * H + h) * 2];
        iS[h] = 1.0f / MS[(b * H + h) * 2 + 1];
    }
    #pragma unroll
    for (int i = 0; i < 2; ++i) {
        const int u = u0 + tid + i * 256;
        float acc = 0.f;
        #pragma unroll
        for (int h = 0; h < H; ++h)
            acc += __expf(energy[((size_t)b * H + h) * U + u] - M[h]) * iS[h];
        attw[(size_t)b * U + u] = acc * 0.25f;
    }
}

// ---- Pass 4: out = combined @ Wout + bout (K-split 8x, atomics) ----------
__global__ __launch_bounds__(256) void outproj_kernel(
    const float* __restrict__ ctx,   // (B,2048)
    const float* __restrict__ Wout,  // (2048,512)
    const float* __restrict__ bout,  // (512)
    float* __restrict__ outv)        // (B,512) pre-zeroed
{
    const int b = blockIdx.y;
    const int j = blockIdx.x * 256 + threadIdx.x;
    const int i0 = blockIdx.z * 256;
    __shared__ float c_s[256];
    c_s[threadIdx.x] = ctx[(size_t)b * (H * D) + i0 + threadIdx.x];
    __syncthreads();

    float acc = (blockIdx.z == 0) ? bout[j] : 0.f;
    #pragma unroll 8
    for (int i = 0; i < 256; ++i)
        acc += c_s[i] * Wout[(size_t)(i0 + i) * AU + j];
    atomicAdd(&outv[(size_t)b * AU + j], acc);
}

extern "C" void kernel_launch(void* const* d_in, const int* in_sizes, int n_in,
                              void* d_out, int out_size, void* d_ws, size_t ws_size,
                              hipStream_t stream) {
    const float* dec   = (const float*)d_in[0];
    const float* enc   = (const float*)d_in[1];
    const float* prevw = (const float*)d_in[2];
    const float* Wphi  = (const float*)d_in[3];
    const float* bphi  = (const float*)d_in[4];
    const float* Wpsi  = (const float*)d_in[5];
    const float* bpsi  = (const float*)d_in[6];
    const float* convk = (const float*)d_in[7];
    const float* Wloc  = (const float*)d_in[8];
    const float* Wout  = (const float*)d_in[9];
    const float* bout  = (const float*)d_in[10];

    float* out  = (float*)d_out;
    float* outv = out;            // (B,512) context_vector
    float* attw = out + B * AU;   // (B,U) attention_weights

    float* ws        = (float*)d_ws;
    float* ws_v      = ws;                        // 65536
    float* ws_const  = ws + 65536;                // 128
    float* ws_ck     = ws + 65664;                // 124 (pad to 65792)
    float* ws_energy = ws + 65792;                // B*H*U = 524288
    float* ws_pctx   = ws_energy + (size_t)B*H*U;            // B*BPB*H*512 = 2097152
    float* ws_pms    = ws_pctx + (size_t)B*BPB*H*D;          // B*BPB*H*2 = 8192
    float* ws_MS     = ws_pms + (size_t)B*BPB*H*2;           // 256
    float* ws_ctx    = ws_MS + 256;                          // B*H*512 = 65536

    hipMemsetAsync(outv, 0, (size_t)B * AU * sizeof(float), stream);

    prep_kernel<<<dim3(B * H), 256, 0, stream>>>(dec, Wphi, bphi, Wpsi, bpsi,
                                                 convk, Wloc, ws_v, ws_const, ws_ck);
    fused_pass1<<<dim3(BPB, B), 256, 0, stream>>>(enc, prevw, ws_v, ws_const,
                                                  ws_ck, ws_energy, ws_pctx, ws_pms);
    combine_kernel<<<dim3(B * H), 256, 0, stream>>>(ws_pctx, ws_pms, ws_ctx, ws_MS);
    attw_kernel<<<dim3(8, B), 256, 0, stream>>>(ws_energy, ws_MS, attw);
    outproj_kernel<<<dim3(2, B, 8), 256, 0, stream>>>(ws_ctx, Wout, bout, outv);
}